// Round 1
// 83.434 us; speedup vs baseline: 1.0261x; 1.0261x over previous
//
#include <hip/hip_runtime.h>

#define HW    (128*128)
#define DHW   (128*128*128)
#define NTOT  (4*DHW)
#define NBLK  1024         // reduce blocks: 4 batches * 16 z-chunks(8z) * 16 y-tiles(8y)

__device__ __forceinline__ float sigf(float x){ return 1.0f/(1.0f+__expf(-x)); }
__device__ __forceinline__ float4 ld4(const float* p){ return *(const float4*)p; }

// ws float layout: p_occ[NBLK], p_surf[NBLK], p_over[NBLK], p_trap[4]

// ---------------------------------------------------------------------------
// mega_k: heterogeneous grid of 4+NBLK blocks.
//   blocks 0..3   : resin-trap 16^3 box sim (one per batch), hidden under reduce.
//   blocks 4..    : occ/surface/overhang reduction — STREAMING rewrite.
// Reduce path (new): thread owns (z, x4-column), walks 8 y-rows. 3x3 support
// of the below plane = x-window via 2 shuffles + y-window via a 3-row rolling
// register window (P[i],P[i+1],P[i+2]). No LDS staging, no per-step barriers;
// 18 independent float4 loads per thread issued straight-line. Below-plane
// rows are re-read, but thread z+1's below-stream leads thread z's curr-stream
// by one row in the same block -> L1/L2 hit, HBM fetch ~= 1.2x input.
// ---------------------------------------------------------------------------
__global__ __launch_bounds__(256, 4) void mega_k(
    const float* __restrict__ v, float* __restrict__ p_occ,
    float* __restrict__ p_surf, float* __restrict__ p_over,
    float* __restrict__ p_trap)
{
    __shared__ float4 smem4[1445];          // 5780 floats (trap needs all of it)
    __shared__ float sred[16];
    float* smem = (float*)smem4;

    const int bid = blockIdx.x;
    const int tid = threadIdx.x;
    const float4 zero4 = make_float4(0,0,0,0);

    if (bid < 4) {
        // ================= trap box path (unchanged, verified) =============
        const int b = bid;
        const size_t gb = (size_t)b * DHW;
        const int ty = tid & 15, tz = tid >> 4;
        const float a_lo = sigf(-10.0f), a_hi = sigf(10.0f);
        #define M(zz,yy) (smem + (((zz)*17 + (yy))*20))

        float m[16], nv[16];
        {
            const float* rv = v + gb + ((size_t)tz*128 + ty)*128;
            int dzy = abs(tz-5) + abs(ty-5);
            #pragma unroll
            for (int q = 0; q < 4; ++q) {
                int x4 = 4*q;
                float4 a = ld4(rv + x4);
                nv[x4+0]=1.f-a.x; nv[x4+1]=1.f-a.y; nv[x4+2]=1.f-a.z; nv[x4+3]=1.f-a.w;
                int d0=dzy+abs(x4+0-5), d1=dzy+abs(x4+1-5);
                int d2=dzy+abs(x4+2-5), d3=dzy+abs(x4+3-5);
                m[x4+0] = ((d0==0)?1.f:((d0==1)?a_hi:a_lo)) * nv[x4+0];
                m[x4+1] = ((d1==0)?1.f:((d1==1)?a_hi:a_lo)) * nv[x4+1];
                m[x4+2] = ((d2==0)?1.f:((d2==1)?a_hi:a_lo)) * nv[x4+2];
                m[x4+3] = ((d3==0)?1.f:((d3==1)?a_hi:a_lo)) * nv[x4+3];
                *(float4*)(M(tz,ty) + x4) = make_float4(m[x4+0],m[x4+1],m[x4+2],m[x4+3]);
            }
        }
        const float xrE = a_lo * (1.f - v[gb + ((size_t)tz*128 + ty)*128 + 16]);
        {
            int a = tid >> 4, e = tid & 15;
            M(16,a)[e] = a_lo * (1.f - v[gb + ((size_t)16*128 + a)*128 + e]);
            M(a,16)[e] = a_lo * (1.f - v[gb + ((size_t)a*128 + 16)*128 + e]);
        }
        __syncthreads();

        for (int it = 0; it < 9; ++it) {
            const float* YM = M(tz,ty-1);
            const float* YP = M(tz,ty+1);
            const float* ZM = M(tz-1,ty);
            const float* ZP = M(tz+1,ty);
            float nm[16];
            #pragma unroll
            for (int q = 0; q < 4; ++q) {
                int x4 = 4*q;
                float4 ym = (ty > 0) ? *(const float4*)(YM + x4) : zero4;
                float4 yp = *(const float4*)(YP + x4);
                float4 zm = (tz > 0) ? *(const float4*)(ZM + x4) : zero4;
                float4 zp = *(const float4*)(ZP + x4);
                float xl = (q == 0) ? 0.f : m[x4-1];
                float xr = (q == 3) ? xrE : m[x4+4];
                float s0 = xl      + m[x4+1] + ym.x + yp.x + zm.x + zp.x;
                float s1 = m[x4+0] + m[x4+2] + ym.y + yp.y + zm.y + zp.y;
                float s2 = m[x4+1] + m[x4+3] + ym.z + yp.z + zm.z + zp.z;
                float s3 = m[x4+2] + xr      + ym.w + yp.w + zm.w + zp.w;
                nm[x4+0] = fmaxf(m[x4+0], sigf(20.f*s0 - 10.f)) * nv[x4+0];
                nm[x4+1] = fmaxf(m[x4+1], sigf(20.f*s1 - 10.f)) * nv[x4+1];
                nm[x4+2] = fmaxf(m[x4+2], sigf(20.f*s2 - 10.f)) * nv[x4+2];
                nm[x4+3] = fmaxf(m[x4+3], sigf(20.f*s3 - 10.f)) * nv[x4+3];
            }
            __syncthreads();
            float* W = M(tz,ty);
            #pragma unroll
            for (int q = 0; q < 4; ++q) {
                int x4 = 4*q;
                *(float4*)(W + x4) = make_float4(nm[x4+0],nm[x4+1],nm[x4+2],nm[x4+3]);
                m[x4+0]=nm[x4+0]; m[x4+1]=nm[x4+1]; m[x4+2]=nm[x4+2]; m[x4+3]=nm[x4+3];
            }
            __syncthreads();
        }

        float d = 0.f;
        #pragma unroll
        for (int x = 0; x < 16; ++x) d += m[x] - a_lo * nv[x];
        #pragma unroll
        for (int o = 32; o; o >>= 1) d += __shfl_down(d, o, 64);
        int lane = tid & 63, wid = tid >> 6;
        if (lane == 0) sred[wid] = d;
        __syncthreads();
        if (tid == 0) p_trap[b] = sred[0] + sred[1] + sred[2] + sred[3];
        #undef M
    } else {
        // ================= streaming reduce path =================
        const int rid = bid - 4;                 // 0..1023
        const int b   = rid >> 8;                // batch
        const int rem = rid & 255;
        const int z0  = (rem >> 4) * 8;          // z-chunk of 8
        const int y0  = (rem & 15) * 8;          // y-tile of 8
        const int tx  = tid & 31;                // x column (4 floats)
        const int tz  = tid >> 5;                // 0..7
        const int z   = z0 + tz;
        const int x4  = tx * 4;
        const size_t gb = (size_t)b * DHW;
        const float* cp = v + gb + (size_t)z * HW;   // curr plane z
        const float* bp = cp - HW;                   // below plane z-1

        float occ = 0.f, surf = 0.f, over = 0.f;

        // ---- phase 1: issue all below-plane loads (rows y0-1 .. y0+8) ----
        float4 qb[10];
        if (z >= 1) {
            #pragma unroll
            for (int r = 0; r < 10; ++r) {
                int gy = y0 - 1 + r;
                qb[r] = ((unsigned)gy <= 127u) ? ld4(bp + gy*128 + x4) : zero4;
            }
        }
        // ---- phase 2: issue all curr-plane loads (rows y0 .. y0+7) ----
        float4 qc[8];
        #pragma unroll
        for (int i = 0; i < 8; ++i) qc[i] = ld4(cp + (y0+i)*128 + x4);

        // ---- phase 3: x-windowed 3-sums of the below rows (2 shuffles/row)
        float4 P[10];
        if (z >= 1) {
            #pragma unroll
            for (int r = 0; r < 10; ++r) {
                float4 q = qb[r];
                float ql = __shfl_up(q.w, 1);   if (tx == 0)  ql = 0.f;
                float qr = __shfl_down(q.x, 1); if (tx == 31) qr = 0.f;
                P[r] = make_float4(ql+q.x+q.y, q.x+q.y+q.z,
                                   q.y+q.z+q.w, q.z+q.w+qr);
            }
        }

        // ---- phase 4: accumulate ----
        const float wz  = (z==0 || z==127) ? 2.f : 3.f;
        const float wx0 = (x4==0)   ? 2.f : 3.f;
        const float wx3 = (x4==124) ? 2.f : 3.f;
        const float inv9 = 1.f/9.f;
        #pragma unroll
        for (int i = 0; i < 8; ++i) {
            const int y = y0 + i;
            float4 val = qc[i];
            occ += val.x + val.y + val.z + val.w;
            float wy = (y==0 || y==127) ? 2.f : 3.f;
            surf += wz*wy*(wx0*val.x + 3.f*val.y + 3.f*val.z + wx3*val.w);
            if (z >= 1) {
                float4 a = P[i], c = P[i+1], d = P[i+2];   // rows y-1, y, y+1
                float4 S = make_float4(a.x+c.x+d.x, a.y+c.y+d.y,
                                       a.z+c.z+d.z, a.w+c.w+d.w);
                over += val.x*(1.f - S.x*inv9) + val.y*(1.f - S.y*inv9)
                      + val.z*(1.f - S.z*inv9) + val.w*(1.f - S.w*inv9);
            }
        }

        #pragma unroll
        for (int o = 32; o; o >>= 1) {
            occ  += __shfl_down(occ,  o, 64);
            surf += __shfl_down(surf, o, 64);
            over += __shfl_down(over, o, 64);
        }
        int lane = tid & 63, wid = tid >> 6;
        if (lane == 0) { sred[wid]=occ; sred[4+wid]=surf; sred[8+wid]=over; }
        __syncthreads();
        if (tid == 0) {
            p_occ [rid] = sred[0]+sred[1]+sred[2]+sred[3];
            p_surf[rid] = sred[4]+sred[5]+sred[6]+sred[7];
            p_over[rid] = sred[8]+sred[9]+sred[10]+sred[11];
        }
    }
}

// ---------------------------------------------------------------------------
// finalize: sum partials (f64), combine with trap deltas.
// trap_sum = a_lo*(N - sum(v)) + sum(box deltas)
// ---------------------------------------------------------------------------
__global__ __launch_bounds__(1024) void finalize_k(
    const float* __restrict__ p_occ, const float* __restrict__ p_surf,
    const float* __restrict__ p_over, const float* __restrict__ p_trap,
    float* __restrict__ out)
{
    double occ=0, surf=0, over=0;
    for (int i = threadIdx.x; i < NBLK; i += 1024) {
        occ += p_occ[i]; surf += p_surf[i]; over += p_over[i];
    }
    __shared__ double sm[3][16];
    #pragma unroll
    for (int o = 32; o; o >>= 1) {
        occ  += __shfl_down(occ,  o, 64);
        surf += __shfl_down(surf, o, 64);
        over += __shfl_down(over, o, 64);
    }
    int lane = threadIdx.x & 63, wid = threadIdx.x >> 6;
    if (lane == 0) { sm[0][wid]=occ; sm[1][wid]=surf; sm[2][wid]=over; }
    __syncthreads();
    if (threadIdx.x == 0) {
        double so=0, ss=0, sv=0;
        for (int w = 0; w < 16; ++w) { so+=sm[0][w]; ss+=sm[1][w]; sv+=sm[2][w]; }
        double dS = (double)p_trap[0] + p_trap[1] + p_trap[2] + p_trap[3];
        double a_lo = 1.0 / (1.0 + exp(10.0));
        double N = (double)NTOT;
        double trap_sum = a_lo * (N - so) + dS;
        double occupancy = so / N;
        double occ_pen = 10.0 * (occupancy - 0.5) * (occupancy - 0.5);
        out[0] = (float)(sv / N);
        out[1] = (float)(ss / 27.0 / N - 100.0 * trap_sum / N - occ_pen);
    }
}

extern "C" void kernel_launch(void* const* d_in, const int* in_sizes, int n_in,
                              void* d_out, int out_size, void* d_ws, size_t ws_size,
                              hipStream_t stream)
{
    const float* v = (const float*)d_in[0];
    float* out = (float*)d_out;
    float* ws = (float*)d_ws;

    float* p_occ  = ws;
    float* p_surf = p_occ  + NBLK;
    float* p_over = p_surf + NBLK;
    float* p_trap = p_over + NBLK;   // 4 floats

    mega_k<<<NBLK + 4, 256, 0, stream>>>(v, p_occ, p_surf, p_over, p_trap);
    finalize_k<<<1, 1024, 0, stream>>>(p_occ, p_surf, p_over, p_trap, out);
}